// Round 6
// baseline (158.328 us; speedup 1.0000x reference)
//
#include <hip/hip_runtime.h>

// MaskTypeProbabilitiesLayer: per (b,t) produce 8-wide 0/1 mask (int32 output —
// the harness maps the reference's bool output to int32, proven by round-5
// absmax == bitpattern(1.0f)-1 = 1065353215).
//
//   gt = in[b,t,0]  (int32, 0..7)
//   base = TYPE_TABLE[gt]; for gt in {4,5,6} use dynamic mask based on whether
//   a 5 (timesign) / 6 (tempo) appeared at any position <= min(t+1, L-1).
//   Only zero/nonzero of the cumsum matters -> first-occurrence index per row.
//
// Bit-packed masks (bit j = feature j):
//   TYPE_TABLE[0]=0x02  [1]=0x06  [2]=0x10  [3]=0xF8  [7]=0x80  others=0
//   NO_TIMESIGN=0x20  NO_TEMPO=0x40  FULL=0xF8
// Entries 0..7 packed into one 64-bit constant (entry 8 == 0 handled by branch).

#define SEQ_L 2048
#define NF 11
#define BLOCK 256
#define PER_THREAD (SEQ_L / BLOCK)   // 8

__global__ __launch_bounds__(BLOCK)
void mask_type_prob_kernel(const int* __restrict__ in, int* __restrict__ out) {
    __shared__ int s_gt[SEQ_L];
    __shared__ int s_first5;
    __shared__ int s_first6;

    const int b   = blockIdx.x;
    const int tid = threadIdx.x;

    if (tid == 0) { s_first5 = 0x7FFFFFFF; s_first6 = 0x7FFFFFFF; }
    __syncthreads();

    const int* row = in + (size_t)b * SEQ_L * NF;

    int f5 = 0x7FFFFFFF, f6 = 0x7FFFFFFF;
    #pragma unroll
    for (int k = 0; k < PER_THREAD; ++k) {
        const int t = tid + k * BLOCK;
        const int g = row[(size_t)t * NF];   // stride-44B: every cache line touched anyway
        s_gt[t] = g;
        if (g == 5) f5 = min(f5, t);
        if (g == 6) f6 = min(f6, t);
    }
    // Wave-level reduce first (cheap), then one LDS atomic per wave.
    #pragma unroll
    for (int off = 32; off >= 1; off >>= 1) {
        f5 = min(f5, __shfl_xor(f5, off, 64));
        f6 = min(f6, __shfl_xor(f6, off, 64));
    }
    if ((tid & 63) == 0) {
        if (f5 != 0x7FFFFFFF) atomicMin(&s_first5, f5);
        if (f6 != 0x7FFFFFFF) atomicMin(&s_first6, f6);
    }
    __syncthreads();

    const int first5 = s_first5;
    const int first6 = s_first6;

    // base table entries 0..7, 8 bits each
    const unsigned long long pack = 0x80000000F8100602ULL;

    int* orow = out + (size_t)b * SEQ_L * 8;

    #pragma unroll
    for (int k = 0; k < PER_THREAD; ++k) {
        const int t = tid + k * BLOCK;
        const int g = s_gt[t];
        unsigned m;
        if (g >= 4 && g <= 6) {
            const int idx = (t + 1 < SEQ_L - 1) ? (t + 1) : (SEQ_L - 1);
            m = (first5 > idx) ? 0x20u : ((first6 > idx) ? 0x40u : 0xF8u);
        } else {
            int gc = g < 0 ? 0 : (g > 8 ? 8 : g);
            m = (gc >= 8) ? 0u : (unsigned)((pack >> (gc * 8)) & 0xFFu);
        }
        int4 lo, hi;
        lo.x = (int)((m >> 0) & 1u);
        lo.y = (int)((m >> 1) & 1u);
        lo.z = (int)((m >> 2) & 1u);
        lo.w = (int)((m >> 3) & 1u);
        hi.x = (int)((m >> 4) & 1u);
        hi.y = (int)((m >> 5) & 1u);
        hi.z = (int)((m >> 6) & 1u);
        hi.w = (int)((m >> 7) & 1u);
        int4* dst = (int4*)(orow + (size_t)t * 8);
        dst[0] = lo;
        dst[1] = hi;
    }
}

extern "C" void kernel_launch(void* const* d_in, const int* in_sizes, int n_in,
                              void* d_out, int out_size, void* d_ws, size_t ws_size,
                              hipStream_t stream) {
    const int* in = (const int*)d_in[0];
    int* out = (int*)d_out;
    const int batch = in_sizes[0] / (SEQ_L * NF);   // 1024
    mask_type_prob_kernel<<<batch, BLOCK, 0, stream>>>(in, out);
}